// Round 3
// baseline (5176.401 us; speedup 1.0000x reference)
//
#include <hip/hip_runtime.h>
#include <hip/hip_cooperative_groups.h>

namespace cg = cooperative_groups;

#define BATCH    1024
#define UNITS    1024
#define INSTEPS  64
#define OUTSTEPS 32
#define NF       4
#define NSTEPS   (INSTEPS + OUTSTEPS - 1)   // 95

typedef _Float16 half8 __attribute__((ext_vector_type(8)));
typedef float    f32x4 __attribute__((ext_vector_type(4)));

__device__ __forceinline__ float sigf(float x)  { return 1.0f / (1.0f + __expf(-x)); }
__device__ __forceinline__ float tanhf_(float x){ return 1.0f - 2.0f / (__expf(2.0f * x) + 1.0f); }

// One-time: U fp32 [1024 k][4096 n] -> Ut f16 [4096 n][1024 k] (transposed)
__global__ void u_transpose(const float* __restrict__ U, _Float16* __restrict__ Ut) {
    __shared__ _Float16 T[64][72];
    const int tid = threadIdx.x;
    const int bid = blockIdx.x;            // 1024 blocks = 16 (k) x 64 (n)
    const int k0 = (bid >> 6) << 6;
    const int n0 = (bid & 63) << 6;
    #pragma unroll
    for (int i = 0; i < 16; ++i) {
        int q = i * 256 + tid;
        int r = q >> 6, cc = q & 63;
        T[r][cc] = (_Float16)U[(size_t)(k0 + r) * 4096 + n0 + cc];
    }
    __syncthreads();
    #pragma unroll
    for (int i = 0; i < 16; ++i) {
        int q = i * 256 + tid;
        int nn = q >> 6, kk = q & 63;
        Ut[(size_t)(n0 + nn) * 1024 + k0 + kk] = T[kk][nn];
    }
}

// Persistent cooperative kernel: all 95 LSTM steps in one launch.
// 256 blocks (1/CU) x 512 threads (8 waves). Block = 256 rows x (4 gates x 16 units).
// B-tile (64 cols x 1024 K f16) pinned in LDS for the whole sequence; c-state in
// registers; h ping-pongs in global f16; A-frags direct from global (line-coalesced).
// K-loop has NO barriers; one __syncthreads (xt) + one grid.sync() per step.
#define LDS_BYTES (16*64*72*2 + 256*4*4)   // Bs + xs = 151552

__global__ __launch_bounds__(512, 2) void lstm_seq(
    const float* __restrict__ x, const float* __restrict__ W,
    const float* __restrict__ bias, const float* __restrict__ Wd,
    const float* __restrict__ bd, const _Float16* __restrict__ Ut,
    _Float16* hA, _Float16* hB, float* out)
{
    extern __shared__ __align__(16) char smem[];
    _Float16 (*Bs)[64][72] = (_Float16 (*)[64][72])smem;       // [16 chunks][64 rows][72]
    float (*xs)[NF] = (float (*)[NF])(smem + 16*64*72*2);      // [256][4]

    cg::grid_group grid = cg::this_grid();

    const int tid = threadIdx.x;
    const int bid = blockIdx.x;
    const int m0 = (bid >> 6) << 8;        // 4 m-tiles of 256 rows
    const int u0 = (bid & 63) << 4;        // 64 u-tiles of 16 units

    const int lane = tid & 63;
    const int wv   = tid >> 6;             // 0..7
    const int quad = lane >> 4;
    const int ln   = lane & 15;

    // ---- stage B-tile into LDS once (64 rows x 1024 K) ----
    {
        const int r_st  = tid >> 3;                    // 0..63
        const int koffs = (tid & 7) << 3;              // 0..56
        const int grow  = ((r_st >> 4) << 10) + u0 + (r_st & 15);
        const _Float16* bsrc = Ut + (size_t)grow * UNITS;
        #pragma unroll
        for (int kc = 0; kc < 16; ++kc)
            *(float4*)&Bs[kc][r_st][koffs] = *(const float4*)(bsrc + kc * 64 + koffs);
    }

    // ---- hoisted weights for epilogue ----
    float wt[4][4], bt[4];
    #pragma unroll
    for (int g = 0; g < 4; ++g) {
        int col = (g << 10) + u0 + ln;
        bt[g] = bias[col];
        #pragma unroll
        for (int f = 0; f < 4; ++f) wt[g][f] = W[f * 4096 + col];
    }
    const float* wdp = Wd + (size_t)(u0 + ln) * NF;
    float wd0 = wdp[0], wd1 = wdp[1], wd2 = wdp[2], wd3 = wdp[3];
    float bd0 = 0, bd1 = 0, bd2 = 0, bd3 = 0;
    if ((bid & 63) == 0) { bd0 = bd[0]; bd1 = bd[1]; bd2 = bd[2]; bd3 = bd[3]; }

    float cr[2][4] = {{0,0,0,0},{0,0,0,0}};   // c-state, fp32, in registers

    __syncthreads();   // Bs ready

    for (int p = 0; p < NSTEPS; ++p) {
        // ---- stage xt (fp32) ----
        #pragma unroll
        for (int i = 0; i < 2; ++i) {
            int q = i * 512 + tid;
            int r = q >> 2, f = q & 3;
            xs[r][f] = (p < INSTEPS)
                     ? x[(size_t)(m0 + r) * (INSTEPS * NF) + p * NF + f]
                     : out[(size_t)(m0 + r) * (OUTSTEPS * NF) + (p - INSTEPS) * NF + f];
        }
        __syncthreads();

        f32x4 acc[2][4] = {};

        if (p > 0) {
            const _Float16* hr = (p & 1) ? hA : hB;   // written at step p-1
            const _Float16* ap0 = hr + (size_t)(m0 + wv * 32 + ln) * UNITS + quad * 8;
            const _Float16* ap1 = ap0 + (size_t)16 * UNITS;

            half8 a00 = *(const half8*)(ap0);
            half8 a01 = *(const half8*)(ap0 + 32);
            half8 a10 = *(const half8*)(ap1);
            half8 a11 = *(const half8*)(ap1 + 32);

            #pragma unroll 1
            for (int kc = 0; kc < 16; ++kc) {
                half8 af0 = a00, ag0 = a01, af1 = a10, ag1 = a11;
                if (kc < 15) {                      // prefetch next chunk
                    int kb = (kc + 1) * 64;
                    a00 = *(const half8*)(ap0 + kb);
                    a01 = *(const half8*)(ap0 + kb + 32);
                    a10 = *(const half8*)(ap1 + kb);
                    a11 = *(const half8*)(ap1 + kb + 32);
                }
                const _Float16 (*B)[72] = Bs[kc];
                half8 bf0 = *(const half8*)&B[ln][quad * 8];
                half8 bf1 = *(const half8*)&B[16 + ln][quad * 8];
                half8 bf2 = *(const half8*)&B[32 + ln][quad * 8];
                half8 bf3 = *(const half8*)&B[48 + ln][quad * 8];
                acc[0][0] = __builtin_amdgcn_mfma_f32_16x16x32_f16(af0, bf0, acc[0][0], 0, 0, 0);
                acc[1][0] = __builtin_amdgcn_mfma_f32_16x16x32_f16(af1, bf0, acc[1][0], 0, 0, 0);
                acc[0][1] = __builtin_amdgcn_mfma_f32_16x16x32_f16(af0, bf1, acc[0][1], 0, 0, 0);
                acc[1][1] = __builtin_amdgcn_mfma_f32_16x16x32_f16(af1, bf1, acc[1][1], 0, 0, 0);
                acc[0][2] = __builtin_amdgcn_mfma_f32_16x16x32_f16(af0, bf2, acc[0][2], 0, 0, 0);
                acc[1][2] = __builtin_amdgcn_mfma_f32_16x16x32_f16(af1, bf2, acc[1][2], 0, 0, 0);
                acc[0][3] = __builtin_amdgcn_mfma_f32_16x16x32_f16(af0, bf3, acc[0][3], 0, 0, 0);
                acc[1][3] = __builtin_amdgcn_mfma_f32_16x16x32_f16(af1, bf3, acc[1][3], 0, 0, 0);
                half8 bg0 = *(const half8*)&B[ln][32 + quad * 8];
                half8 bg1 = *(const half8*)&B[16 + ln][32 + quad * 8];
                half8 bg2 = *(const half8*)&B[32 + ln][32 + quad * 8];
                half8 bg3 = *(const half8*)&B[48 + ln][32 + quad * 8];
                acc[0][0] = __builtin_amdgcn_mfma_f32_16x16x32_f16(ag0, bg0, acc[0][0], 0, 0, 0);
                acc[1][0] = __builtin_amdgcn_mfma_f32_16x16x32_f16(ag1, bg0, acc[1][0], 0, 0, 0);
                acc[0][1] = __builtin_amdgcn_mfma_f32_16x16x32_f16(ag0, bg1, acc[0][1], 0, 0, 0);
                acc[1][1] = __builtin_amdgcn_mfma_f32_16x16x32_f16(ag1, bg1, acc[1][1], 0, 0, 0);
                acc[0][2] = __builtin_amdgcn_mfma_f32_16x16x32_f16(ag0, bg2, acc[0][2], 0, 0, 0);
                acc[1][2] = __builtin_amdgcn_mfma_f32_16x16x32_f16(ag1, bg2, acc[1][2], 0, 0, 0);
                acc[0][3] = __builtin_amdgcn_mfma_f32_16x16x32_f16(ag0, bg3, acc[0][3], 0, 0, 0);
                acc[1][3] = __builtin_amdgcn_mfma_f32_16x16x32_f16(ag1, bg3, acc[1][3], 0, 0, 0);
            }
        }

        // ---- epilogue ----
        _Float16* hw = (p & 1) ? hB : hA;
        const int s_out = p - (INSTEPS - 1);
        #pragma unroll
        for (int r = 0; r < 2; ++r) {
            #pragma unroll
            for (int i = 0; i < 4; ++i) {
                int rl = wv * 32 + r * 16 + quad * 4 + i;   // C/D: row=quad*4+reg, col=ln
                int R  = m0 + rl;
                float x0 = xs[rl][0], x1 = xs[rl][1], x2 = xs[rl][2], x3 = xs[rl][3];
                float zi = acc[r][0][i] + bt[0] + x0*wt[0][0] + x1*wt[0][1] + x2*wt[0][2] + x3*wt[0][3];
                float zf = acc[r][1][i] + bt[1] + x0*wt[1][0] + x1*wt[1][1] + x2*wt[1][2] + x3*wt[1][3];
                float zg = acc[r][2][i] + bt[2] + x0*wt[2][0] + x1*wt[2][1] + x2*wt[2][2] + x3*wt[2][3];
                float zo = acc[r][3][i] + bt[3] + x0*wt[3][0] + x1*wt[3][1] + x2*wt[3][2] + x3*wt[3][3];
                float cold = cr[r][i];
                float si = sigf(zi), sf = sigf(zf), so = sigf(zo);
                float cn = sf * cold + si * tanhf_(zg);
                float hn = so * tanhf_(cn);
                cr[r][i] = cn;
                hw[(size_t)R * UNITS + u0 + ln] = (_Float16)hn;
                if (s_out >= 0) {
                    float p0 = hn * wd0, p1 = hn * wd1, p2 = hn * wd2, p3 = hn * wd3;
                    #pragma unroll
                    for (int mk = 1; mk < 16; mk <<= 1) {
                        p0 += __shfl_xor(p0, mk);
                        p1 += __shfl_xor(p1, mk);
                        p2 += __shfl_xor(p2, mk);
                        p3 += __shfl_xor(p3, mk);
                    }
                    if (ln == 0) {
                        float* op = out + (size_t)R * (OUTSTEPS * NF) + s_out * NF;
                        atomicAdd(op + 0, p0 + bd0);
                        atomicAdd(op + 1, p1 + bd1);
                        atomicAdd(op + 2, p2 + bd2);
                        atomicAdd(op + 3, p3 + bd3);
                    }
                }
            }
        }

        grid.sync();   // h/out visible device-wide before next step
    }
}

extern "C" void kernel_launch(void* const* d_in, const int* in_sizes, int n_in,
                              void* d_out, int out_size, void* d_ws, size_t ws_size,
                              hipStream_t stream) {
    (void)in_sizes; (void)n_in; (void)ws_size;
    const float* x  = (const float*)d_in[0];
    const float* W  = (const float*)d_in[1];
    const float* U  = (const float*)d_in[2];
    const float* b  = (const float*)d_in[3];
    const float* Wd = (const float*)d_in[4];
    const float* bd = (const float*)d_in[5];
    float* out = (float*)d_out;

    char* ws = (char*)d_ws;
    _Float16* hA = (_Float16*)ws;                     // 2 MB  h ping
    _Float16* hB = (_Float16*)(ws + (2 << 20));       // 2 MB  h pong
    _Float16* Ut = (_Float16*)(ws + (4 << 20));       // 8 MB  U^T f16

    hipMemsetAsync(d_out, 0, (size_t)out_size * sizeof(float), stream); // preds accumulate
    u_transpose<<<1024, 256, 0, stream>>>(U, Ut);

    hipFuncSetAttribute((const void*)lstm_seq,
                        hipFuncAttributeMaxDynamicSharedMemorySize, LDS_BYTES);

    void* args[] = {(void*)&x, (void*)&W, (void*)&b, (void*)&Wd, (void*)&bd,
                    (void*)&Ut, (void*)&hA, (void*)&hB, (void*)&out};
    hipLaunchCooperativeKernel((const void*)lstm_seq, dim3(256), dim3(512),
                               args, LDS_BYTES, stream);
}

// Round 4
// 2946.690 us; speedup vs baseline: 1.7567x; 1.7567x over previous
//
#include <hip/hip_runtime.h>

#define BATCH    1024
#define UNITS    1024
#define INSTEPS  64
#define OUTSTEPS 32
#define NF       4
#define NSTEPS   (INSTEPS + OUTSTEPS - 1)   // 95

typedef _Float16 half8 __attribute__((ext_vector_type(8)));
typedef float    f32x4 __attribute__((ext_vector_type(4)));

__device__ __forceinline__ float sigf(float x)  { return 1.0f / (1.0f + __expf(-x)); }
__device__ __forceinline__ float tanhf_(float x){ return 1.0f - 2.0f / (__expf(2.0f * x) + 1.0f); }

// One-time: U fp32 [1024 k][4096 n] -> Ut f16 [4096 n][1024 k] (transposed)
__global__ void u_transpose(const float* __restrict__ U, _Float16* __restrict__ Ut) {
    __shared__ _Float16 T[64][72];
    const int tid = threadIdx.x;
    const int bid = blockIdx.x;            // 1024 blocks = 16 (k) x 64 (n)
    const int k0 = (bid >> 6) << 6;
    const int n0 = (bid & 63) << 6;
    #pragma unroll
    for (int i = 0; i < 16; ++i) {
        int q = i * 256 + tid;
        int r = q >> 6, cc = q & 63;
        T[r][cc] = (_Float16)U[(size_t)(k0 + r) * 4096 + n0 + cc];
    }
    __syncthreads();
    #pragma unroll
    for (int i = 0; i < 16; ++i) {
        int q = i * 256 + tid;
        int nn = q >> 6, kk = q & 63;
        Ut[(size_t)(n0 + nn) * 1024 + k0 + kk] = T[kk][nn];
    }
}

// Persistent cooperative kernel, all 95 steps. 256 blocks (1/CU) x 512 threads.
// Block = 256-row m-band x 16 units (64 gate-cols). m-band = bid&3 so each XCD's
// 32 blocks share ONE 512KB h-band. B pinned in LDS whole run; c in registers;
// h ping-pongs in global f16 via AGENT-SCOPE stores (straight to LLC -> no dirty-L2
// writeback at the barrier); A-frags direct-global with DEPTH-4 prefetch.
// Custom 2-level tree barrier (8 per-XCD counters + root flag) replaces grid.sync.
#define LDS_BYTES (16*64*72*2 + 256*4*4)   // Bs + xs = 151552

__global__ __launch_bounds__(512, 2) void lstm_seq(
    const float* __restrict__ x, const float* __restrict__ W,
    const float* __restrict__ bias, const float* __restrict__ Wd,
    const float* __restrict__ bd, const _Float16* __restrict__ Ut,
    _Float16* hA, _Float16* hB, float* out, unsigned* bar)
{
    extern __shared__ __align__(16) char smem[];
    _Float16 (*Bs)[64][72] = (_Float16 (*)[64][72])smem;       // [16 chunks][64 rows][72]
    float (*xs)[NF] = (float (*)[NF])(smem + 16*64*72*2);      // [256][4]

    const int tid = threadIdx.x;
    const int bid = blockIdx.x;
    const int m0 = (bid & 3) << 8;         // m-band: all blocks on an XCD share one band
    const int u0 = (bid >> 2) << 4;        // 64 u-tiles of 16 units

    const int lane = tid & 63;
    const int wv   = tid >> 6;             // 0..7
    const int quad = lane >> 4;
    const int ln   = lane & 15;

    unsigned* cnt  = bar;                  // 8 counters, stride 32 dwords
    unsigned* flag = bar + 512;

    // ---- stage B-tile into LDS once (64 gate-cols x 1024 K) ----
    {
        const int r_st  = tid >> 3;                    // 0..63
        const int koffs = (tid & 7) << 3;              // 0..56
        const int grow  = ((r_st >> 4) << 10) + u0 + (r_st & 15);
        const _Float16* bsrc = Ut + (size_t)grow * UNITS;
        #pragma unroll
        for (int kc = 0; kc < 16; ++kc)
            *(float4*)&Bs[kc][r_st][koffs] = *(const float4*)(bsrc + kc * 64 + koffs);
    }

    // ---- hoisted weights ----
    float wt[4][4], bt[4];
    #pragma unroll
    for (int g = 0; g < 4; ++g) {
        int col = (g << 10) + u0 + ln;
        bt[g] = bias[col];
        #pragma unroll
        for (int f = 0; f < 4; ++f) wt[g][f] = W[f * 4096 + col];
    }
    const float* wdp = Wd + (size_t)(u0 + ln) * NF;
    float wd0 = wdp[0], wd1 = wdp[1], wd2 = wdp[2], wd3 = wdp[3];
    float bd0 = 0, bd1 = 0, bd2 = 0, bd3 = 0;
    if (u0 == 0) { bd0 = bd[0]; bd1 = bd[1]; bd2 = bd[2]; bd3 = bd[3]; }

    float cr[2][4] = {{0,0,0,0},{0,0,0,0}};   // c-state in registers

    // prefetch xt for step 0
    const int xr = tid >> 2, xf = tid & 3;
    float xp0 = x[(size_t)(m0 + xr) * (INSTEPS * NF) + xf];
    float xp1 = x[(size_t)(m0 + 128 + xr) * (INSTEPS * NF) + xf];

    __syncthreads();   // Bs ready

    for (int p = 0; p < NSTEPS; ++p) {
        xs[xr][xf]       = xp0;
        xs[128 + xr][xf] = xp1;
        __syncthreads();

        f32x4 acc[2][4] = {};

        if (p > 0) {
            const _Float16* hrp = (p & 1) ? hA : hB;   // written at step p-1
            const _Float16* ap0 = hrp + (size_t)(m0 + wv * 32 + ln) * UNITS + quad * 8;
            const _Float16* ap1 = ap0 + (size_t)16 * UNITS;

            half8 ar[4][4];
            #pragma unroll
            for (int d = 0; d < 4; ++d) {              // depth-4 prefetch pipeline
                ar[d][0] = *(const half8*)(ap0 + d * 64);
                ar[d][1] = *(const half8*)(ap0 + d * 64 + 32);
                ar[d][2] = *(const half8*)(ap1 + d * 64);
                ar[d][3] = *(const half8*)(ap1 + d * 64 + 32);
            }

            #pragma unroll
            for (int kc = 0; kc < 16; ++kc) {          // fully unrolled: static slot idx
                const int sl = kc & 3;
                half8 af0 = ar[sl][0], ag0 = ar[sl][1], af1 = ar[sl][2], ag1 = ar[sl][3];
                if (kc < 12) {
                    const _Float16* a0 = ap0 + (kc + 4) * 64;
                    const _Float16* a1 = ap1 + (kc + 4) * 64;
                    ar[sl][0] = *(const half8*)(a0);
                    ar[sl][1] = *(const half8*)(a0 + 32);
                    ar[sl][2] = *(const half8*)(a1);
                    ar[sl][3] = *(const half8*)(a1 + 32);
                }
                const _Float16 (*B)[72] = Bs[kc];
                half8 bf0 = *(const half8*)&B[ln][quad * 8];
                half8 bf1 = *(const half8*)&B[16 + ln][quad * 8];
                half8 bf2 = *(const half8*)&B[32 + ln][quad * 8];
                half8 bf3 = *(const half8*)&B[48 + ln][quad * 8];
                acc[0][0] = __builtin_amdgcn_mfma_f32_16x16x32_f16(af0, bf0, acc[0][0], 0, 0, 0);
                acc[1][0] = __builtin_amdgcn_mfma_f32_16x16x32_f16(af1, bf0, acc[1][0], 0, 0, 0);
                acc[0][1] = __builtin_amdgcn_mfma_f32_16x16x32_f16(af0, bf1, acc[0][1], 0, 0, 0);
                acc[1][1] = __builtin_amdgcn_mfma_f32_16x16x32_f16(af1, bf1, acc[1][1], 0, 0, 0);
                acc[0][2] = __builtin_amdgcn_mfma_f32_16x16x32_f16(af0, bf2, acc[0][2], 0, 0, 0);
                acc[1][2] = __builtin_amdgcn_mfma_f32_16x16x32_f16(af1, bf2, acc[1][2], 0, 0, 0);
                acc[0][3] = __builtin_amdgcn_mfma_f32_16x16x32_f16(af0, bf3, acc[0][3], 0, 0, 0);
                acc[1][3] = __builtin_amdgcn_mfma_f32_16x16x32_f16(af1, bf3, acc[1][3], 0, 0, 0);
                half8 bg0 = *(const half8*)&B[ln][32 + quad * 8];
                half8 bg1 = *(const half8*)&B[16 + ln][32 + quad * 8];
                half8 bg2 = *(const half8*)&B[32 + ln][32 + quad * 8];
                half8 bg3 = *(const half8*)&B[48 + ln][32 + quad * 8];
                acc[0][0] = __builtin_amdgcn_mfma_f32_16x16x32_f16(ag0, bg0, acc[0][0], 0, 0, 0);
                acc[1][0] = __builtin_amdgcn_mfma_f32_16x16x32_f16(ag1, bg0, acc[1][0], 0, 0, 0);
                acc[0][1] = __builtin_amdgcn_mfma_f32_16x16x32_f16(ag0, bg1, acc[0][1], 0, 0, 0);
                acc[1][1] = __builtin_amdgcn_mfma_f32_16x16x32_f16(ag1, bg1, acc[1][1], 0, 0, 0);
                acc[0][2] = __builtin_amdgcn_mfma_f32_16x16x32_f16(ag0, bg2, acc[0][2], 0, 0, 0);
                acc[1][2] = __builtin_amdgcn_mfma_f32_16x16x32_f16(ag1, bg2, acc[1][2], 0, 0, 0);
                acc[0][3] = __builtin_amdgcn_mfma_f32_16x16x32_f16(ag0, bg3, acc[0][3], 0, 0, 0);
                acc[1][3] = __builtin_amdgcn_mfma_f32_16x16x32_f16(ag1, bg3, acc[1][3], 0, 0, 0);
            }
        }

        // ---- epilogue: gates, c/h update, fused pred ----
        _Float16* hw = (p & 1) ? hB : hA;
        const int s_out = p - (INSTEPS - 1);
        #pragma unroll
        for (int r = 0; r < 2; ++r) {
            #pragma unroll
            for (int i = 0; i < 4; ++i) {
                int rl = wv * 32 + r * 16 + quad * 4 + i;   // C/D: row=quad*4+reg, col=ln
                int R  = m0 + rl;
                float x0 = xs[rl][0], x1 = xs[rl][1], x2 = xs[rl][2], x3 = xs[rl][3];
                float zi = acc[r][0][i] + bt[0] + x0*wt[0][0] + x1*wt[0][1] + x2*wt[0][2] + x3*wt[0][3];
                float zf = acc[r][1][i] + bt[1] + x0*wt[1][0] + x1*wt[1][1] + x2*wt[1][2] + x3*wt[1][3];
                float zg = acc[r][2][i] + bt[2] + x0*wt[2][0] + x1*wt[2][1] + x2*wt[2][2] + x3*wt[2][3];
                float zo = acc[r][3][i] + bt[3] + x0*wt[3][0] + x1*wt[3][1] + x2*wt[3][2] + x3*wt[3][3];
                float cold = cr[r][i];
                float si = sigf(zi), sf = sigf(zf), so = sigf(zo);
                float cn = sf * cold + si * tanhf_(zg);
                float hn = so * tanhf_(cn);
                cr[r][i] = cn;
                // agent-scope store: lands in LLC, no dirty-L2 writeback at barrier
                unsigned short hv = __builtin_bit_cast(unsigned short, (_Float16)hn);
                __hip_atomic_store((unsigned short*)&hw[(size_t)R * UNITS + u0 + ln], hv,
                                   __ATOMIC_RELAXED, __HIP_MEMORY_SCOPE_AGENT);
                if (s_out >= 0) {
                    float p0 = hn * wd0, p1 = hn * wd1, p2 = hn * wd2, p3 = hn * wd3;
                    #pragma unroll
                    for (int mk = 1; mk < 16; mk <<= 1) {
                        p0 += __shfl_xor(p0, mk);
                        p1 += __shfl_xor(p1, mk);
                        p2 += __shfl_xor(p2, mk);
                        p3 += __shfl_xor(p3, mk);
                    }
                    if (ln == 0) {
                        float* op = out + (size_t)R * (OUTSTEPS * NF) + s_out * NF;
                        atomicAdd(op + 0, p0 + bd0);
                        atomicAdd(op + 1, p1 + bd1);
                        atomicAdd(op + 2, p2 + bd2);
                        atomicAdd(op + 3, p3 + bd3);
                    }
                }
            }
        }

        const int pn = p + 1;
        if (pn < INSTEPS) {                        // prefetch next xt (input window)
            xp0 = x[(size_t)(m0 + xr) * (INSTEPS * NF) + pn * NF + xf];
            xp1 = x[(size_t)(m0 + 128 + xr) * (INSTEPS * NF) + pn * NF + xf];
        }

        // ---- 2-level tree barrier ----
        __syncthreads();                           // all waves' stores drained (vmcnt)
        if (tid == 0) {
            __builtin_amdgcn_fence(__ATOMIC_RELEASE, "agent");
            __hip_atomic_fetch_add(&cnt[(bid & 7) * 32], 1u,
                                   __ATOMIC_RELAXED, __HIP_MEMORY_SCOPE_AGENT);
            const unsigned tgt = (unsigned)pn * 32u;
            if (bid == 0) {
                #pragma unroll 1
                for (int g = 0; g < 8; ++g)
                    while (__hip_atomic_load(&cnt[g * 32], __ATOMIC_RELAXED,
                                             __HIP_MEMORY_SCOPE_AGENT) < tgt)
                        __builtin_amdgcn_s_sleep(1);
                __builtin_amdgcn_fence(__ATOMIC_ACQ_REL, "agent");
                __hip_atomic_store(flag, (unsigned)pn,
                                   __ATOMIC_RELAXED, __HIP_MEMORY_SCOPE_AGENT);
            }
            while (__hip_atomic_load(flag, __ATOMIC_RELAXED,
                                     __HIP_MEMORY_SCOPE_AGENT) < (unsigned)pn)
                __builtin_amdgcn_s_sleep(1);
            __builtin_amdgcn_fence(__ATOMIC_ACQUIRE, "agent");   // invalidate L1/L2
        }
        __syncthreads();

        if (pn >= INSTEPS && pn < NSTEPS) {        // decode: next xt = last prediction
            int s = pn - INSTEPS;
            xp0 = __hip_atomic_load(&out[(size_t)(m0 + xr) * (OUTSTEPS * NF) + s * NF + xf],
                                    __ATOMIC_RELAXED, __HIP_MEMORY_SCOPE_AGENT);
            xp1 = __hip_atomic_load(&out[(size_t)(m0 + 128 + xr) * (OUTSTEPS * NF) + s * NF + xf],
                                    __ATOMIC_RELAXED, __HIP_MEMORY_SCOPE_AGENT);
        }
    }
}

extern "C" void kernel_launch(void* const* d_in, const int* in_sizes, int n_in,
                              void* d_out, int out_size, void* d_ws, size_t ws_size,
                              hipStream_t stream) {
    (void)in_sizes; (void)n_in; (void)ws_size;
    const float* x  = (const float*)d_in[0];
    const float* W  = (const float*)d_in[1];
    const float* U  = (const float*)d_in[2];
    const float* b  = (const float*)d_in[3];
    const float* Wd = (const float*)d_in[4];
    const float* bd = (const float*)d_in[5];
    float* out = (float*)d_out;

    char* ws = (char*)d_ws;
    _Float16* hA  = (_Float16*)ws;                    // 2 MB  h ping
    _Float16* hB  = (_Float16*)(ws + (2 << 20));      // 2 MB  h pong
    _Float16* Ut  = (_Float16*)(ws + (4 << 20));      // 8 MB  U^T f16
    unsigned* bar = (unsigned*)(ws + (12 << 20));     // 4 KB  barrier state

    hipMemsetAsync(bar, 0, 4096, stream);                               // counters+flag
    hipMemsetAsync(d_out, 0, (size_t)out_size * sizeof(float), stream); // preds accumulate
    u_transpose<<<1024, 256, 0, stream>>>(U, Ut);

    hipFuncSetAttribute((const void*)lstm_seq,
                        hipFuncAttributeMaxDynamicSharedMemorySize, LDS_BYTES);

    void* args[] = {(void*)&x, (void*)&W, (void*)&b, (void*)&Wd, (void*)&bd,
                    (void*)&Ut, (void*)&hA, (void*)&hB, (void*)&out, (void*)&bar};
    hipLaunchCooperativeKernel((const void*)lstm_seq, dim3(256), dim3(512),
                               args, LDS_BYTES, stream);
}

// Round 5
// 2382.044 us; speedup vs baseline: 2.1731x; 1.2370x over previous
//
#include <hip/hip_runtime.h>

#define BATCH    1024
#define UNITS    1024
#define INSTEPS  64
#define OUTSTEPS 32
#define NF       4
#define NSTEPS   (INSTEPS + OUTSTEPS - 1)   // 95

typedef _Float16 half8 __attribute__((ext_vector_type(8)));
typedef float    f32x4 __attribute__((ext_vector_type(4)));

__device__ __forceinline__ float sigf(float x)  { return 1.0f / (1.0f + __expf(-x)); }
__device__ __forceinline__ float tanhf_(float x){ return 1.0f - 2.0f / (__expf(2.0f * x) + 1.0f); }

// One-time: U fp32 [1024 k][4096 n] -> Ut f16 [4096 n][1024 k] (transposed)
__global__ void u_transpose(const float* __restrict__ U, _Float16* __restrict__ Ut) {
    __shared__ _Float16 T[64][72];
    const int tid = threadIdx.x;
    const int bid = blockIdx.x;            // 1024 blocks = 16 (k) x 64 (n)
    const int k0 = (bid >> 6) << 6;
    const int n0 = (bid & 63) << 6;
    #pragma unroll
    for (int i = 0; i < 16; ++i) {
        int q = i * 256 + tid;
        int r = q >> 6, cc = q & 63;
        T[r][cc] = (_Float16)U[(size_t)(k0 + r) * 4096 + n0 + cc];
    }
    __syncthreads();
    #pragma unroll
    for (int i = 0; i < 16; ++i) {
        int q = i * 256 + tid;
        int nn = q >> 6, kk = q & 63;
        Ut[(size_t)(n0 + nn) * 1024 + k0 + kk] = T[kk][nn];
    }
}

// Persistent cooperative kernel, all 95 steps. 256 blocks (1/CU) x 512 threads.
// band = bid&3 (256 rows); u-tile = bid>>2 (16 units). Blocks of band b live on
// XCD pair {b, b+4} (bid%8 round-robin) and are the ONLY writers+readers of that
// band's h and out rows -> 4 independent 64-block barriers instead of one
// device-wide barrier. B pinned in LDS (XOR-swizzled, conflict-free); c in regs;
// h agent-scope stores (straight to LLC); A direct-global depth-4 prefetch.
#define LDS_BYTES (16*64*64*2 + 256*4*4)   // Bs + xs = 135168

__global__ __launch_bounds__(512, 2) void lstm_seq(
    const float* __restrict__ x, const float* __restrict__ W,
    const float* __restrict__ bias, const float* __restrict__ Wd,
    const float* __restrict__ bd, const _Float16* __restrict__ Ut,
    _Float16* hA, _Float16* hB, float* out, unsigned* bar)
{
    extern __shared__ __align__(16) char smem[];
    _Float16 (*Bs)[64][64] = (_Float16 (*)[64][64])smem;       // [16 chunks][64 rows][64]
    float (*xs)[NF] = (float (*)[NF])(smem + 16*64*64*2);      // [256][4]

    const int tid  = threadIdx.x;
    const int bid  = blockIdx.x;
    const int band = bid & 3;
    const int m0   = band << 8;            // 256-row band, XCD-pair local
    const int u0   = (bid >> 2) << 4;      // 64 u-tiles of 16 units

    const int lane = tid & 63;
    const int wv   = tid >> 6;             // 0..7
    const int quad = lane >> 4;
    const int ln   = lane & 15;

    unsigned* cnt = bar + band * 64;       // per-band counter, 256B apart

    // ---- stage B-tile into LDS once, XOR-swizzled on 16B chunks ----
    {
        const int r_st = tid >> 3;                     // 0..63
        const int ck   = tid & 7;                      // logical 16B chunk
        const int swz  = ((ck ^ (r_st & 7)) << 3);     // physical half-offset
        const int grow = ((r_st >> 4) << 10) + u0 + (r_st & 15);
        const _Float16* bsrc = Ut + (size_t)grow * UNITS + ck * 8;
        #pragma unroll
        for (int kc = 0; kc < 16; ++kc)
            *(float4*)&Bs[kc][r_st][swz] = *(const float4*)(bsrc + kc * 64);
    }

    // ---- hoisted weights ----
    float wt[4][4], bt[4];
    #pragma unroll
    for (int g = 0; g < 4; ++g) {
        int col = (g << 10) + u0 + ln;
        bt[g] = bias[col];
        #pragma unroll
        for (int f = 0; f < 4; ++f) wt[g][f] = W[f * 4096 + col];
    }
    const float* wdp = Wd + (size_t)(u0 + ln) * NF;
    float wd0 = wdp[0], wd1 = wdp[1], wd2 = wdp[2], wd3 = wdp[3];
    float bd0 = 0, bd1 = 0, bd2 = 0, bd3 = 0;
    if (u0 == 0) { bd0 = bd[0]; bd1 = bd[1]; bd2 = bd[2]; bd3 = bd[3]; }

    float cr[2][4] = {{0,0,0,0},{0,0,0,0}};   // c-state in registers

    // swizzled B-frag read offsets (row&7 == ln&7 for all four row groups)
    const int swz0 = ((quad ^ (ln & 7)) << 3);   // k-sub 0
    const int swz1 = swz0 ^ 32;                  // k-sub 1 (chunk 4+quad)

    // prefetch xt for step 0
    const int xr = tid >> 2, xf = tid & 3;
    float xp0 = x[(size_t)(m0 + xr) * (INSTEPS * NF) + xf];
    float xp1 = x[(size_t)(m0 + 128 + xr) * (INSTEPS * NF) + xf];

    __syncthreads();   // Bs ready

    for (int p = 0; p < NSTEPS; ++p) {
        xs[xr][xf]       = xp0;
        xs[128 + xr][xf] = xp1;
        __syncthreads();

        f32x4 acc[2][4] = {};

        if (p > 0) {
            const _Float16* hrp = (p & 1) ? hA : hB;   // written at step p-1
            const _Float16* ap0 = hrp + (size_t)(m0 + wv * 32 + ln) * UNITS + quad * 8;
            const _Float16* ap1 = ap0 + (size_t)16 * UNITS;

            half8 ar[4][4];
            #pragma unroll
            for (int d = 0; d < 4; ++d) {              // depth-4 prefetch pipeline
                ar[d][0] = *(const half8*)(ap0 + d * 64);
                ar[d][1] = *(const half8*)(ap0 + d * 64 + 32);
                ar[d][2] = *(const half8*)(ap1 + d * 64);
                ar[d][3] = *(const half8*)(ap1 + d * 64 + 32);
            }

            #pragma unroll
            for (int kc = 0; kc < 16; ++kc) {          // fully unrolled
                const int sl = kc & 3;
                half8 af0 = ar[sl][0], ag0 = ar[sl][1], af1 = ar[sl][2], ag1 = ar[sl][3];
                if (kc < 12) {
                    const _Float16* a0 = ap0 + (kc + 4) * 64;
                    const _Float16* a1 = ap1 + (kc + 4) * 64;
                    ar[sl][0] = *(const half8*)(a0);
                    ar[sl][1] = *(const half8*)(a0 + 32);
                    ar[sl][2] = *(const half8*)(a1);
                    ar[sl][3] = *(const half8*)(a1 + 32);
                }
                const _Float16 (*B)[64] = Bs[kc];
                half8 bf0 = *(const half8*)&B[ln][swz0];
                half8 bf1 = *(const half8*)&B[16 + ln][swz0];
                half8 bf2 = *(const half8*)&B[32 + ln][swz0];
                half8 bf3 = *(const half8*)&B[48 + ln][swz0];
                acc[0][0] = __builtin_amdgcn_mfma_f32_16x16x32_f16(af0, bf0, acc[0][0], 0, 0, 0);
                acc[1][0] = __builtin_amdgcn_mfma_f32_16x16x32_f16(af1, bf0, acc[1][0], 0, 0, 0);
                acc[0][1] = __builtin_amdgcn_mfma_f32_16x16x32_f16(af0, bf1, acc[0][1], 0, 0, 0);
                acc[1][1] = __builtin_amdgcn_mfma_f32_16x16x32_f16(af1, bf1, acc[1][1], 0, 0, 0);
                acc[0][2] = __builtin_amdgcn_mfma_f32_16x16x32_f16(af0, bf2, acc[0][2], 0, 0, 0);
                acc[1][2] = __builtin_amdgcn_mfma_f32_16x16x32_f16(af1, bf2, acc[1][2], 0, 0, 0);
                acc[0][3] = __builtin_amdgcn_mfma_f32_16x16x32_f16(af0, bf3, acc[0][3], 0, 0, 0);
                acc[1][3] = __builtin_amdgcn_mfma_f32_16x16x32_f16(af1, bf3, acc[1][3], 0, 0, 0);
                half8 bg0 = *(const half8*)&B[ln][swz1];
                half8 bg1 = *(const half8*)&B[16 + ln][swz1];
                half8 bg2 = *(const half8*)&B[32 + ln][swz1];
                half8 bg3 = *(const half8*)&B[48 + ln][swz1];
                acc[0][0] = __builtin_amdgcn_mfma_f32_16x16x32_f16(ag0, bg0, acc[0][0], 0, 0, 0);
                acc[1][0] = __builtin_amdgcn_mfma_f32_16x16x32_f16(ag1, bg0, acc[1][0], 0, 0, 0);
                acc[0][1] = __builtin_amdgcn_mfma_f32_16x16x32_f16(ag0, bg1, acc[0][1], 0, 0, 0);
                acc[1][1] = __builtin_amdgcn_mfma_f32_16x16x32_f16(ag1, bg1, acc[1][1], 0, 0, 0);
                acc[0][2] = __builtin_amdgcn_mfma_f32_16x16x32_f16(ag0, bg2, acc[0][2], 0, 0, 0);
                acc[1][2] = __builtin_amdgcn_mfma_f32_16x16x32_f16(ag1, bg2, acc[1][2], 0, 0, 0);
                acc[0][3] = __builtin_amdgcn_mfma_f32_16x16x32_f16(ag0, bg3, acc[0][3], 0, 0, 0);
                acc[1][3] = __builtin_amdgcn_mfma_f32_16x16x32_f16(ag1, bg3, acc[1][3], 0, 0, 0);
            }
        }

        // ---- epilogue: gates, c/h update, fused pred ----
        _Float16* hw = (p & 1) ? hB : hA;
        const int s_out = p - (INSTEPS - 1);
        #pragma unroll
        for (int r = 0; r < 2; ++r) {
            #pragma unroll
            for (int i = 0; i < 4; ++i) {
                int rl = wv * 32 + r * 16 + quad * 4 + i;   // C/D: row=quad*4+reg, col=ln
                int R  = m0 + rl;
                float x0 = xs[rl][0], x1 = xs[rl][1], x2 = xs[rl][2], x3 = xs[rl][3];
                float zi = acc[r][0][i] + bt[0] + x0*wt[0][0] + x1*wt[0][1] + x2*wt[0][2] + x3*wt[0][3];
                float zf = acc[r][1][i] + bt[1] + x0*wt[1][0] + x1*wt[1][1] + x2*wt[1][2] + x3*wt[1][3];
                float zg = acc[r][2][i] + bt[2] + x0*wt[2][0] + x1*wt[2][1] + x2*wt[2][2] + x3*wt[2][3];
                float zo = acc[r][3][i] + bt[3] + x0*wt[3][0] + x1*wt[3][1] + x2*wt[3][2] + x3*wt[3][3];
                float cold = cr[r][i];
                float si = sigf(zi), sf = sigf(zf), so = sigf(zo);
                float cn = sf * cold + si * tanhf_(zg);
                float hn = so * tanhf_(cn);
                cr[r][i] = cn;
                // agent-scope store: lands in LLC, no dirty-L2 writeback at barrier
                unsigned short hv = __builtin_bit_cast(unsigned short, (_Float16)hn);
                __hip_atomic_store((unsigned short*)&hw[(size_t)R * UNITS + u0 + ln], hv,
                                   __ATOMIC_RELAXED, __HIP_MEMORY_SCOPE_AGENT);
                if (s_out >= 0) {
                    float p0 = hn * wd0, p1 = hn * wd1, p2 = hn * wd2, p3 = hn * wd3;
                    #pragma unroll
                    for (int mk = 1; mk < 16; mk <<= 1) {
                        p0 += __shfl_xor(p0, mk);
                        p1 += __shfl_xor(p1, mk);
                        p2 += __shfl_xor(p2, mk);
                        p3 += __shfl_xor(p3, mk);
                    }
                    if (ln == 0) {
                        float* op = out + (size_t)R * (OUTSTEPS * NF) + s_out * NF;
                        atomicAdd(op + 0, p0 + bd0);
                        atomicAdd(op + 1, p1 + bd1);
                        atomicAdd(op + 2, p2 + bd2);
                        atomicAdd(op + 3, p3 + bd3);
                    }
                }
            }
        }

        const int pn = p + 1;
        if (pn < INSTEPS) {                        // prefetch next xt (input window)
            xp0 = x[(size_t)(m0 + xr) * (INSTEPS * NF) + pn * NF + xf];
            xp1 = x[(size_t)(m0 + 128 + xr) * (INSTEPS * NF) + pn * NF + xf];
        }

        // ---- band-local barrier (64 blocks on XCD pair {band, band+4}) ----
        __syncthreads();                           // drains vmcnt: h stores + out atomics at LLC
        if (tid == 0) {
            __hip_atomic_fetch_add(cnt, 1u, __ATOMIC_RELAXED, __HIP_MEMORY_SCOPE_AGENT);
            const unsigned tgt = (unsigned)pn * 64u;
            while (__hip_atomic_load(cnt, __ATOMIC_RELAXED, __HIP_MEMORY_SCOPE_AGENT) < tgt)
                __builtin_amdgcn_s_sleep(1);
            __builtin_amdgcn_fence(__ATOMIC_ACQUIRE, "agent");   // L1/L2 inv
        }
        __syncthreads();

        if (pn >= INSTEPS && pn < NSTEPS) {        // decode: next xt = last prediction
            int s = pn - INSTEPS;
            xp0 = __hip_atomic_load(&out[(size_t)(m0 + xr) * (OUTSTEPS * NF) + s * NF + xf],
                                    __ATOMIC_RELAXED, __HIP_MEMORY_SCOPE_AGENT);
            xp1 = __hip_atomic_load(&out[(size_t)(m0 + 128 + xr) * (OUTSTEPS * NF) + s * NF + xf],
                                    __ATOMIC_RELAXED, __HIP_MEMORY_SCOPE_AGENT);
        }
    }
}

extern "C" void kernel_launch(void* const* d_in, const int* in_sizes, int n_in,
                              void* d_out, int out_size, void* d_ws, size_t ws_size,
                              hipStream_t stream) {
    (void)in_sizes; (void)n_in; (void)ws_size;
    const float* x  = (const float*)d_in[0];
    const float* W  = (const float*)d_in[1];
    const float* U  = (const float*)d_in[2];
    const float* b  = (const float*)d_in[3];
    const float* Wd = (const float*)d_in[4];
    const float* bd = (const float*)d_in[5];
    float* out = (float*)d_out;

    char* ws = (char*)d_ws;
    _Float16* hA  = (_Float16*)ws;                    // 2 MB  h ping
    _Float16* hB  = (_Float16*)(ws + (2 << 20));      // 2 MB  h pong
    _Float16* Ut  = (_Float16*)(ws + (4 << 20));      // 8 MB  U^T f16
    unsigned* bar = (unsigned*)(ws + (12 << 20));     // 4 KB  barrier state

    hipMemsetAsync(bar, 0, 4096, stream);                               // band counters
    hipMemsetAsync(d_out, 0, (size_t)out_size * sizeof(float), stream); // preds accumulate
    u_transpose<<<1024, 256, 0, stream>>>(U, Ut);

    hipFuncSetAttribute((const void*)lstm_seq,
                        hipFuncAttributeMaxDynamicSharedMemorySize, LDS_BYTES);

    void* args[] = {(void*)&x, (void*)&W, (void*)&b, (void*)&Wd, (void*)&bd,
                    (void*)&Ut, (void*)&hA, (void*)&hB, (void*)&out, (void*)&bar};
    hipLaunchCooperativeKernel((const void*)lstm_seq, dim3(256), dim3(512),
                               args, LDS_BYTES, stream);
}